// Round 6
// baseline (349.520 us; speedup 1.0000x reference)
//
#include <hip/hip_runtime.h>
#include <hip/hip_bf16.h>
#include <math.h>

// ---------------------------------------------------------------------------
// three_gcn round 6 (= round 5 with compile fix):
//   Bucket-sort CSR; per layer gemm_ro (MFMA bf16) then agg_act gather.
//   NON-TEMPORAL stores for hrel/hroot/y via clang ext_vector f32x4 (HIP's
//   float4 class is rejected by __builtin_nontemporal_store).
// ---------------------------------------------------------------------------

#define D 64
#define BSHIFT 9
#define BW 512          // dsts per bucket
#define BCAP 8192       // edge capacity per bucket (mean 6400, sigma 80)

typedef __attribute__((ext_vector_type(8))) short short8;
typedef __attribute__((ext_vector_type(4))) float f32x4;

__device__ __forceinline__ ushort f2b(float f) {
    uint x = __float_as_uint(f);
    uint r = (x + 0x7fffu + ((x >> 16) & 1u)) >> 16;   // RNE
    return (ushort)r;
}
__device__ __forceinline__ float b2f(ushort u) {
    return __uint_as_float(((uint)u) << 16);
}

// ---------------- weight convert + bucketCnt zero ----------------

__global__ __launch_bounds__(256) void convert_w(const float* __restrict__ w0,
                                                 const float* __restrict__ w1,
                                                 const float* __restrict__ w2,
                                                 const float* __restrict__ w3,
                                                 const float* __restrict__ w4,
                                                 const float* __restrict__ w5,
                                                 ushort* __restrict__ out,
                                                 int* __restrict__ bucketCnt) {
    if (blockIdx.x == 0 && threadIdx.x < 256) bucketCnt[threadIdx.x] = 0;
    int m = blockIdx.x >> 4;
    int t = (blockIdx.x & 15) * 256 + threadIdx.x;   // 0..4095
    const float* src = m == 0 ? w0 : m == 1 ? w1 : m == 2 ? w2 : m == 3 ? w3 : m == 4 ? w4 : w5;
    int k = t >> 6, d = t & 63;
    out[m * 4096 + d * 64 + k] = f2b(src[t]);
}

// ---------------- CSR pass 1: bucket scatter ----------------

__global__ __launch_bounds__(1024) void bucket_scatter(const int* __restrict__ src,
                                                       const int* __restrict__ dst,
                                                       int* __restrict__ bucketCnt,
                                                       unsigned long long* __restrict__ store,
                                                       int E) {
    __shared__ int h[256], base[256], cur[256];
    int t = threadIdx.x;
    if (t < 256) { h[t] = 0; cur[t] = 0; }
    __syncthreads();
    int e = blockIdx.x * 1024 + t;
    int s = 0, d = 0, b = 0;
    bool ok = e < E;
    if (ok) {
        s = src[e];
        d = dst[e];
        b = d >> BSHIFT;
        atomicAdd(&h[b], 1);
    }
    __syncthreads();
    if (t < 256) base[t] = h[t] ? atomicAdd(&bucketCnt[t], h[t]) : 0;
    __syncthreads();
    if (ok) {
        int r = atomicAdd(&cur[b], 1);
        int pos = base[b] + r;
        if (pos < BCAP)
            store[(size_t)b * BCAP + pos] = ((unsigned long long)(uint)d << 32) | (uint)s;
    }
}

// ---------------- CSR pass 1.5: scan bucket sizes ----------------

__global__ __launch_bounds__(256) void scan_buckets(const int* __restrict__ bucketCnt,
                                                    int* __restrict__ bucketBase,
                                                    int* __restrict__ offs,
                                                    int nb, int n, int E) {
    __shared__ int tmp[256];
    int t = threadIdx.x;
    int v = (t < nb) ? bucketCnt[t] : 0;
    tmp[t] = v;
    __syncthreads();
    for (int off = 1; off < 256; off <<= 1) {
        int add = (t >= off) ? tmp[t - off] : 0;
        __syncthreads();
        tmp[t] += add;
        __syncthreads();
    }
    if (t < nb) bucketBase[t] = tmp[t] - v;
    if (t == 0) offs[n] = E;
}

// ---------------- CSR pass 2: per-bucket counting sort ----------------

__global__ __launch_bounds__(1024) void bucket_build(const int* __restrict__ bucketCnt,
                                                     const int* __restrict__ bucketBase,
                                                     const unsigned long long* __restrict__ store,
                                                     int* __restrict__ offs,
                                                     int* __restrict__ src_sorted, int n) {
    __shared__ int h[BW], loc[BW], cur[BW];
    __shared__ unsigned long long se[BCAP];
    int b = blockIdx.x, t = threadIdx.x;
    int cnt = bucketCnt[b];
    if (cnt > BCAP) cnt = BCAP;
    int obase = bucketBase[b];
    int d0 = b << BSHIFT;
    int nd = n - d0;
    if (nd > BW) nd = BW;
    if (t < BW) { h[t] = 0; cur[t] = 0; }
    __syncthreads();
    for (int i = t; i < cnt; i += 1024) {
        unsigned long long p = store[(size_t)b * BCAP + i];
        se[i] = p;
        atomicAdd(&h[(int)(p >> 32) - d0], 1);
    }
    __syncthreads();
    if (t < BW) loc[t] = h[t];
    __syncthreads();
    for (int off = 1; off < BW; off <<= 1) {
        int add = (t < BW && t >= off) ? loc[t - off] : 0;
        __syncthreads();
        if (t < BW) loc[t] += add;
        __syncthreads();
    }
    if (t < nd) offs[d0 + t] = obase + loc[t] - h[t];   // exclusive
    __syncthreads();
    for (int i = t; i < cnt; i += 1024) {
        unsigned long long p = se[i];
        int dl = (int)(p >> 32) - d0;
        int r = atomicAdd(&cur[dl], 1);
        src_sorted[obase + loc[dl] - h[dl] + r] = (int)(p & 0xffffffffULL);
    }
}

// ---------------- gemm_ro: h_rel = x@Wr (bf16), h_root = x@Wo + b (bf16) ----
// NT stores: hrel/hroot are consumed by random-XCD readers; keep them out of
// this XCD's dirty L2.

__global__ __launch_bounds__(256) void gemm_ro(const float* __restrict__ x,
                                               const ushort* __restrict__ WtR,
                                               const ushort* __restrict__ WtO,
                                               const float* __restrict__ bias,
                                               ushort* __restrict__ hrel,
                                               ushort* __restrict__ hroot, int n) {
    __shared__ ushort hsR[4][16 * 64];
    __shared__ ushort hsO[4][16 * 64];
    int t = threadIdx.x;
    int w = t >> 6, l = t & 63;
    int i0 = blockIdx.x * 64 + w * 16;
    int lr = l & 15, kb = l >> 4;
    int row = i0 + lr;
    int rowc = row < n ? row : n - 1;

    short8 a[2];
#pragma unroll
    for (int s = 0; s < 2; ++s) {
        const float* p = x + (size_t)rowc * D + s * 32 + kb * 8;
        float4 u = *(const float4*)p;
        float4 v = *(const float4*)(p + 4);
        a[s][0] = f2b(u.x); a[s][1] = f2b(u.y); a[s][2] = f2b(u.z); a[s][3] = f2b(u.w);
        a[s][4] = f2b(v.x); a[s][5] = f2b(v.y); a[s][6] = f2b(v.z); a[s][7] = f2b(v.w);
    }

#pragma unroll
    for (int ct = 0; ct < 4; ++ct) {
        f32x4 accR = (f32x4){0.f, 0.f, 0.f, 0.f};
        f32x4 accO = (f32x4){0.f, 0.f, 0.f, 0.f};
#pragma unroll
        for (int s = 0; s < 2; ++s) {
            short8 bR = *(const short8*)(WtR + (ct * 16 + lr) * D + s * 32 + kb * 8);
            short8 bO = *(const short8*)(WtO + (ct * 16 + lr) * D + s * 32 + kb * 8);
            accR = __builtin_amdgcn_mfma_f32_16x16x32_bf16(a[s], bR, accR, 0, 0, 0);
            accO = __builtin_amdgcn_mfma_f32_16x16x32_bf16(a[s], bO, accO, 0, 0, 0);
        }
        float bv = bias[ct * 16 + lr];
#pragma unroll
        for (int i = 0; i < 4; ++i) {
            hsR[w][(kb * 4 + i) * 64 + ct * 16 + lr] = f2b(accR[i]);
            hsO[w][(kb * 4 + i) * 64 + ct * 16 + lr] = f2b(accO[i] + bv);
        }
    }
    __syncthreads();

    int r = l >> 2, ch = l & 3;
    int grow = i0 + r;
    if (grow < n) {
        const f32x4* spR = (const f32x4*)&hsR[w][r * 64 + ch * 16];
        const f32x4* spO = (const f32x4*)&hsO[w][r * 64 + ch * 16];
        f32x4 r0 = spR[0];
        f32x4 r1 = spR[1];
        f32x4 o0 = spO[0];
        f32x4 o1 = spO[1];
        __builtin_nontemporal_store(r0, (f32x4*)(hrel + (size_t)grow * D + ch * 16));
        __builtin_nontemporal_store(r1, (f32x4*)(hrel + (size_t)grow * D + ch * 16 + 8));
        __builtin_nontemporal_store(o0, (f32x4*)(hroot + (size_t)grow * D + ch * 16));
        __builtin_nontemporal_store(o1, (f32x4*)(hroot + (size_t)grow * D + ch * 16 + 8));
    }
}

// ---------------- agg_act: y = act(sum h_rel[src] + h_root) -----------------
// One wave per node; q=l>>4 edge residue mod 4, r=l&15 dims 4r..4r+3.
// NT store for y (re-read linearly by next layer's gemm_ro on another XCD).

template <int ACT>
__global__ __launch_bounds__(256) void agg_act(const ushort* __restrict__ hrel,
                                               const ushort* __restrict__ hroot,
                                               const int* __restrict__ offs,
                                               const int* __restrict__ srcs,
                                               float* __restrict__ y, int n) {
    int node = blockIdx.x * 4 + (threadIdx.x >> 6);
    int l = threadIdx.x & 63;
    if (node >= n) return;
    int q = l >> 4, r = l & 15;
    int beg = offs[node];
    int end = offs[node + 1];

    float a0 = 0.f, a1 = 0.f, a2 = 0.f, a3 = 0.f;
    for (int e0 = beg; e0 < end; e0 += 16) {
#pragma unroll
        for (int k = 0; k < 4; ++k) {
            int ee = e0 + k * 4 + q;
            int eec = ee < end ? ee : end - 1;
            int s = srcs[eec];
            uint2 u = *(const uint2*)(hrel + (size_t)s * D + r * 4);
            float m = (ee < end) ? 1.f : 0.f;
            a0 = fmaf(__uint_as_float(u.x << 16), m, a0);
            a1 = fmaf(__uint_as_float(u.x & 0xffff0000u), m, a1);
            a2 = fmaf(__uint_as_float(u.y << 16), m, a2);
            a3 = fmaf(__uint_as_float(u.y & 0xffff0000u), m, a3);
        }
    }

    a0 += __shfl_xor(a0, 32); a0 += __shfl_xor(a0, 16);
    a1 += __shfl_xor(a1, 32); a1 += __shfl_xor(a1, 16);
    a2 += __shfl_xor(a2, 32); a2 += __shfl_xor(a2, 16);
    a3 += __shfl_xor(a3, 32); a3 += __shfl_xor(a3, 16);

    uint2 hr = *(const uint2*)(hroot + (size_t)node * D + r * 4);
    a0 += __uint_as_float(hr.x << 16);
    a1 += __uint_as_float(hr.x & 0xffff0000u);
    a2 += __uint_as_float(hr.y << 16);
    a3 += __uint_as_float(hr.y & 0xffff0000u);

    if (ACT == 0) {
        a0 = a0 > 0.f ? a0 : expf(a0) - 1.f;
        a1 = a1 > 0.f ? a1 : expf(a1) - 1.f;
        a2 = a2 > 0.f ? a2 : expf(a2) - 1.f;
        a3 = a3 > 0.f ? a3 : expf(a3) - 1.f;
    } else {
        a0 = 1.f / (1.f + expf(-a0));
        a1 = 1.f / (1.f + expf(-a1));
        a2 = 1.f / (1.f + expf(-a2));
        a3 = 1.f / (1.f + expf(-a3));
    }

    if (q == 0) {
        f32x4 o = (f32x4){a0, a1, a2, a3};
        __builtin_nontemporal_store(o, (f32x4*)(y + (size_t)node * D + r * 4));
    }
}

// ---------------- launch ----------------

extern "C" void kernel_launch(void* const* d_in, const int* in_sizes, int n_in,
                              void* d_out, int out_size, void* d_ws, size_t ws_size,
                              hipStream_t stream) {
    const float* graph = (const float*)d_in[0];
    const int* eidx    = (const int*)d_in[1];
    const float* W1r = (const float*)d_in[2];
    const float* W1o = (const float*)d_in[3];
    const float* b1  = (const float*)d_in[4];
    const float* W2r = (const float*)d_in[5];
    const float* W2o = (const float*)d_in[6];
    const float* b2  = (const float*)d_in[7];
    const float* W3r = (const float*)d_in[8];
    const float* W3o = (const float*)d_in[9];
    const float* b3  = (const float*)d_in[10];

    int n = in_sizes[0] / D;     // 100000
    int E = in_sizes[1] / 2;     // 1250000
    const int* src  = eidx;
    const int* dstl = eidx + E;
    int nb = (n + BW - 1) >> BSHIFT;   // 196

    char* w = (char*)d_ws;
    auto carve = [&](size_t bytes) {
        void* p = (void*)w;
        w += (bytes + 255) & ~(size_t)255;
        return p;
    };
    ushort* hrel  = (ushort*)carve((size_t)n * D * sizeof(ushort));   // 12.8 MB
    ushort* hroot = (ushort*)carve((size_t)n * D * sizeof(ushort));   // 12.8 MB
    // bucket store aliases hrel+hroot (dead during CSR build)
    unsigned long long* store = (unsigned long long*)hrel;
    int* offs       = (int*)carve((size_t)(n + 1) * sizeof(int));
    int* src_sorted = (int*)carve((size_t)E * sizeof(int));           // 5 MB
    int* bucketCnt  = (int*)carve(256 * sizeof(int));
    int* bucketBase = (int*)carve(256 * sizeof(int));
    ushort* wt      = (ushort*)carve(6 * 4096 * sizeof(ushort));      // 48 KB
    ushort* wtR1 = wt;
    ushort* wtO1 = wt + 1 * 4096;
    ushort* wtR2 = wt + 2 * 4096;
    ushort* wtO2 = wt + 3 * 4096;
    ushort* wtR3 = wt + 4 * 4096;
    ushort* wtO3 = wt + 5 * 4096;

    int eb1 = (E + 1023) / 1024;   // 1221
    int tb  = (n + 63) / 64;       // 1563
    int ab  = (n + 3) / 4;         // 25000

    convert_w<<<96, 256, 0, stream>>>(W1r, W1o, W2r, W2o, W3r, W3o, wt, bucketCnt);
    bucket_scatter<<<eb1, 1024, 0, stream>>>(src, dstl, bucketCnt, store, E);
    scan_buckets<<<1, 256, 0, stream>>>(bucketCnt, bucketBase, offs, nb, n, E);
    bucket_build<<<nb, 1024, 0, stream>>>(bucketCnt, bucketBase, store, offs, src_sorted, n);

    float* out = (float*)d_out;
    float* y1 = out;
    float* y2 = out + (size_t)n * D;
    float* y3 = out + 2 * (size_t)n * D;

    // layer 1 (ELU)
    gemm_ro<<<tb, 256, 0, stream>>>(graph, wtR1, wtO1, b1, hrel, hroot, n);
    agg_act<0><<<ab, 256, 0, stream>>>(hrel, hroot, offs, src_sorted, y1, n);
    // layer 2 (ELU)
    gemm_ro<<<tb, 256, 0, stream>>>(y1, wtR2, wtO2, b2, hrel, hroot, n);
    agg_act<0><<<ab, 256, 0, stream>>>(hrel, hroot, offs, src_sorted, y2, n);
    // layer 3 (sigmoid)
    gemm_ro<<<tb, 256, 0, stream>>>(y2, wtR3, wtO3, b3, hrel, hroot, n);
    agg_act<1><<<ab, 256, 0, stream>>>(hrel, hroot, offs, src_sorted, y3, n);
}

// Round 7
// 315.099 us; speedup vs baseline: 1.1092x; 1.1092x over previous
//
#include <hip/hip_runtime.h>
#include <hip/hip_bf16.h>
#include <math.h>

// ---------------------------------------------------------------------------
// three_gcn round 7:
//   R4 structure (bucket-sort CSR; per layer gemm_ro MFMA bf16 + agg_act
//   gather). Changes vs R6:
//     - NT stores reverted (R6: cost ~20us net, FETCH unchanged -> theory dead)
//     - agg_act activations: libm expf (~50 instr) -> __expf / rcpf (2 instr).
//       agg_act measured VALU-issue-bound (VALUBusy 71%, ~435 instr/wave).
// ---------------------------------------------------------------------------

#define D 64
#define BSHIFT 9
#define BW 512          // dsts per bucket
#define BCAP 8192       // edge capacity per bucket (mean 6400, sigma 80)

typedef __attribute__((ext_vector_type(8))) short short8;
typedef __attribute__((ext_vector_type(4))) float f32x4;

__device__ __forceinline__ ushort f2b(float f) {
    uint x = __float_as_uint(f);
    uint r = (x + 0x7fffu + ((x >> 16) & 1u)) >> 16;   // RNE
    return (ushort)r;
}
__device__ __forceinline__ float b2f(ushort u) {
    return __uint_as_float(((uint)u) << 16);
}

// ---------------- weight convert + bucketCnt zero ----------------

__global__ __launch_bounds__(256) void convert_w(const float* __restrict__ w0,
                                                 const float* __restrict__ w1,
                                                 const float* __restrict__ w2,
                                                 const float* __restrict__ w3,
                                                 const float* __restrict__ w4,
                                                 const float* __restrict__ w5,
                                                 ushort* __restrict__ out,
                                                 int* __restrict__ bucketCnt) {
    if (blockIdx.x == 0 && threadIdx.x < 256) bucketCnt[threadIdx.x] = 0;
    int m = blockIdx.x >> 4;
    int t = (blockIdx.x & 15) * 256 + threadIdx.x;   // 0..4095
    const float* src = m == 0 ? w0 : m == 1 ? w1 : m == 2 ? w2 : m == 3 ? w3 : m == 4 ? w4 : w5;
    int k = t >> 6, d = t & 63;
    out[m * 4096 + d * 64 + k] = f2b(src[t]);
}

// ---------------- CSR pass 1: bucket scatter ----------------

__global__ __launch_bounds__(1024) void bucket_scatter(const int* __restrict__ src,
                                                       const int* __restrict__ dst,
                                                       int* __restrict__ bucketCnt,
                                                       unsigned long long* __restrict__ store,
                                                       int E) {
    __shared__ int h[256], base[256], cur[256];
    int t = threadIdx.x;
    if (t < 256) { h[t] = 0; cur[t] = 0; }
    __syncthreads();
    int e = blockIdx.x * 1024 + t;
    int s = 0, d = 0, b = 0;
    bool ok = e < E;
    if (ok) {
        s = src[e];
        d = dst[e];
        b = d >> BSHIFT;
        atomicAdd(&h[b], 1);
    }
    __syncthreads();
    if (t < 256) base[t] = h[t] ? atomicAdd(&bucketCnt[t], h[t]) : 0;
    __syncthreads();
    if (ok) {
        int r = atomicAdd(&cur[b], 1);
        int pos = base[b] + r;
        if (pos < BCAP)
            store[(size_t)b * BCAP + pos] = ((unsigned long long)(uint)d << 32) | (uint)s;
    }
}

// ---------------- CSR pass 1.5: scan bucket sizes ----------------

__global__ __launch_bounds__(256) void scan_buckets(const int* __restrict__ bucketCnt,
                                                    int* __restrict__ bucketBase,
                                                    int* __restrict__ offs,
                                                    int nb, int n, int E) {
    __shared__ int tmp[256];
    int t = threadIdx.x;
    int v = (t < nb) ? bucketCnt[t] : 0;
    tmp[t] = v;
    __syncthreads();
    for (int off = 1; off < 256; off <<= 1) {
        int add = (t >= off) ? tmp[t - off] : 0;
        __syncthreads();
        tmp[t] += add;
        __syncthreads();
    }
    if (t < nb) bucketBase[t] = tmp[t] - v;
    if (t == 0) offs[n] = E;
}

// ---------------- CSR pass 2: per-bucket counting sort ----------------

__global__ __launch_bounds__(1024) void bucket_build(const int* __restrict__ bucketCnt,
                                                     const int* __restrict__ bucketBase,
                                                     const unsigned long long* __restrict__ store,
                                                     int* __restrict__ offs,
                                                     int* __restrict__ src_sorted, int n) {
    __shared__ int h[BW], loc[BW], cur[BW];
    __shared__ unsigned long long se[BCAP];
    int b = blockIdx.x, t = threadIdx.x;
    int cnt = bucketCnt[b];
    if (cnt > BCAP) cnt = BCAP;
    int obase = bucketBase[b];
    int d0 = b << BSHIFT;
    int nd = n - d0;
    if (nd > BW) nd = BW;
    if (t < BW) { h[t] = 0; cur[t] = 0; }
    __syncthreads();
    for (int i = t; i < cnt; i += 1024) {
        unsigned long long p = store[(size_t)b * BCAP + i];
        se[i] = p;
        atomicAdd(&h[(int)(p >> 32) - d0], 1);
    }
    __syncthreads();
    if (t < BW) loc[t] = h[t];
    __syncthreads();
    for (int off = 1; off < BW; off <<= 1) {
        int add = (t < BW && t >= off) ? loc[t - off] : 0;
        __syncthreads();
        if (t < BW) loc[t] += add;
        __syncthreads();
    }
    if (t < nd) offs[d0 + t] = obase + loc[t] - h[t];   // exclusive
    __syncthreads();
    for (int i = t; i < cnt; i += 1024) {
        unsigned long long p = se[i];
        int dl = (int)(p >> 32) - d0;
        int r = atomicAdd(&cur[dl], 1);
        src_sorted[obase + loc[dl] - h[dl] + r] = (int)(p & 0xffffffffULL);
    }
}

// ---------------- gemm_ro: h_rel = x@Wr (bf16), h_root = x@Wo + b (bf16) ----

__global__ __launch_bounds__(256) void gemm_ro(const float* __restrict__ x,
                                               const ushort* __restrict__ WtR,
                                               const ushort* __restrict__ WtO,
                                               const float* __restrict__ bias,
                                               ushort* __restrict__ hrel,
                                               ushort* __restrict__ hroot, int n) {
    __shared__ ushort hsR[4][16 * 64];
    __shared__ ushort hsO[4][16 * 64];
    int t = threadIdx.x;
    int w = t >> 6, l = t & 63;
    int i0 = blockIdx.x * 64 + w * 16;
    int lr = l & 15, kb = l >> 4;
    int row = i0 + lr;
    int rowc = row < n ? row : n - 1;

    short8 a[2];
#pragma unroll
    for (int s = 0; s < 2; ++s) {
        const float* p = x + (size_t)rowc * D + s * 32 + kb * 8;
        float4 u = *(const float4*)p;
        float4 v = *(const float4*)(p + 4);
        a[s][0] = f2b(u.x); a[s][1] = f2b(u.y); a[s][2] = f2b(u.z); a[s][3] = f2b(u.w);
        a[s][4] = f2b(v.x); a[s][5] = f2b(v.y); a[s][6] = f2b(v.z); a[s][7] = f2b(v.w);
    }

#pragma unroll
    for (int ct = 0; ct < 4; ++ct) {
        f32x4 accR = (f32x4){0.f, 0.f, 0.f, 0.f};
        f32x4 accO = (f32x4){0.f, 0.f, 0.f, 0.f};
#pragma unroll
        for (int s = 0; s < 2; ++s) {
            short8 bR = *(const short8*)(WtR + (ct * 16 + lr) * D + s * 32 + kb * 8);
            short8 bO = *(const short8*)(WtO + (ct * 16 + lr) * D + s * 32 + kb * 8);
            accR = __builtin_amdgcn_mfma_f32_16x16x32_bf16(a[s], bR, accR, 0, 0, 0);
            accO = __builtin_amdgcn_mfma_f32_16x16x32_bf16(a[s], bO, accO, 0, 0, 0);
        }
        float bv = bias[ct * 16 + lr];
#pragma unroll
        for (int i = 0; i < 4; ++i) {
            hsR[w][(kb * 4 + i) * 64 + ct * 16 + lr] = f2b(accR[i]);
            hsO[w][(kb * 4 + i) * 64 + ct * 16 + lr] = f2b(accO[i] + bv);
        }
    }
    __syncthreads();

    int r = l >> 2, ch = l & 3;
    int grow = i0 + r;
    if (grow < n) {
        const float4* spR = (const float4*)&hsR[w][r * 64 + ch * 16];
        const float4* spO = (const float4*)&hsO[w][r * 64 + ch * 16];
        float4 r0 = spR[0];
        float4 r1 = spR[1];
        float4 o0 = spO[0];
        float4 o1 = spO[1];
        *(float4*)(hrel + (size_t)grow * D + ch * 16) = r0;
        *(float4*)(hrel + (size_t)grow * D + ch * 16 + 8) = r1;
        *(float4*)(hroot + (size_t)grow * D + ch * 16) = o0;
        *(float4*)(hroot + (size_t)grow * D + ch * 16 + 8) = o1;
    }
}

// ---------------- agg_act: y = act(sum h_rel[src] + h_root) -----------------
// One wave per node; q=l>>4 edge residue mod 4, r=l&15 dims 4r..4r+3.
// Fast activations: __expf (v_mul+v_exp) and v_rcp; libm expf was ~200
// VALU instrs/wave of the measured 435 (VALUBusy 71%).

template <int ACT>
__global__ __launch_bounds__(256) void agg_act(const ushort* __restrict__ hrel,
                                               const ushort* __restrict__ hroot,
                                               const int* __restrict__ offs,
                                               const int* __restrict__ srcs,
                                               float* __restrict__ y, int n) {
    int node = blockIdx.x * 4 + (threadIdx.x >> 6);
    int l = threadIdx.x & 63;
    if (node >= n) return;
    int q = l >> 4, r = l & 15;
    int beg = offs[node];
    int end = offs[node + 1];

    float a0 = 0.f, a1 = 0.f, a2 = 0.f, a3 = 0.f;
    for (int e0 = beg; e0 < end; e0 += 16) {
#pragma unroll
        for (int k = 0; k < 4; ++k) {
            int ee = e0 + k * 4 + q;
            int eec = ee < end ? ee : end - 1;
            int s = srcs[eec];
            uint2 u = *(const uint2*)(hrel + (size_t)s * D + r * 4);
            float m = (ee < end) ? 1.f : 0.f;
            a0 = fmaf(__uint_as_float(u.x << 16), m, a0);
            a1 = fmaf(__uint_as_float(u.x & 0xffff0000u), m, a1);
            a2 = fmaf(__uint_as_float(u.y << 16), m, a2);
            a3 = fmaf(__uint_as_float(u.y & 0xffff0000u), m, a3);
        }
    }

    a0 += __shfl_xor(a0, 32); a0 += __shfl_xor(a0, 16);
    a1 += __shfl_xor(a1, 32); a1 += __shfl_xor(a1, 16);
    a2 += __shfl_xor(a2, 32); a2 += __shfl_xor(a2, 16);
    a3 += __shfl_xor(a3, 32); a3 += __shfl_xor(a3, 16);

    uint2 hr = *(const uint2*)(hroot + (size_t)node * D + r * 4);
    a0 += __uint_as_float(hr.x << 16);
    a1 += __uint_as_float(hr.x & 0xffff0000u);
    a2 += __uint_as_float(hr.y << 16);
    a3 += __uint_as_float(hr.y & 0xffff0000u);

    if (ACT == 0) {
        a0 = a0 > 0.f ? a0 : __expf(a0) - 1.f;
        a1 = a1 > 0.f ? a1 : __expf(a1) - 1.f;
        a2 = a2 > 0.f ? a2 : __expf(a2) - 1.f;
        a3 = a3 > 0.f ? a3 : __expf(a3) - 1.f;
    } else {
        a0 = __builtin_amdgcn_rcpf(1.f + __expf(-a0));
        a1 = __builtin_amdgcn_rcpf(1.f + __expf(-a1));
        a2 = __builtin_amdgcn_rcpf(1.f + __expf(-a2));
        a3 = __builtin_amdgcn_rcpf(1.f + __expf(-a3));
    }

    if (q == 0) {
        float4 o; o.x = a0; o.y = a1; o.z = a2; o.w = a3;
        *(float4*)(y + (size_t)node * D + r * 4) = o;
    }
}

// ---------------- launch ----------------

extern "C" void kernel_launch(void* const* d_in, const int* in_sizes, int n_in,
                              void* d_out, int out_size, void* d_ws, size_t ws_size,
                              hipStream_t stream) {
    const float* graph = (const float*)d_in[0];
    const int* eidx    = (const int*)d_in[1];
    const float* W1r = (const float*)d_in[2];
    const float* W1o = (const float*)d_in[3];
    const float* b1  = (const float*)d_in[4];
    const float* W2r = (const float*)d_in[5];
    const float* W2o = (const float*)d_in[6];
    const float* b2  = (const float*)d_in[7];
    const float* W3r = (const float*)d_in[8];
    const float* W3o = (const float*)d_in[9];
    const float* b3  = (const float*)d_in[10];

    int n = in_sizes[0] / D;     // 100000
    int E = in_sizes[1] / 2;     // 1250000
    const int* src  = eidx;
    const int* dstl = eidx + E;
    int nb = (n + BW - 1) >> BSHIFT;   // 196

    char* w = (char*)d_ws;
    auto carve = [&](size_t bytes) {
        void* p = (void*)w;
        w += (bytes + 255) & ~(size_t)255;
        return p;
    };
    ushort* hrel  = (ushort*)carve((size_t)n * D * sizeof(ushort));   // 12.8 MB
    ushort* hroot = (ushort*)carve((size_t)n * D * sizeof(ushort));   // 12.8 MB
    // bucket store aliases hrel+hroot (dead during CSR build)
    unsigned long long* store = (unsigned long long*)hrel;
    int* offs       = (int*)carve((size_t)(n + 1) * sizeof(int));
    int* src_sorted = (int*)carve((size_t)E * sizeof(int));           // 5 MB
    int* bucketCnt  = (int*)carve(256 * sizeof(int));
    int* bucketBase = (int*)carve(256 * sizeof(int));
    ushort* wt      = (ushort*)carve(6 * 4096 * sizeof(ushort));      // 48 KB
    ushort* wtR1 = wt;
    ushort* wtO1 = wt + 1 * 4096;
    ushort* wtR2 = wt + 2 * 4096;
    ushort* wtO2 = wt + 3 * 4096;
    ushort* wtR3 = wt + 4 * 4096;
    ushort* wtO3 = wt + 5 * 4096;

    int eb1 = (E + 1023) / 1024;   // 1221
    int tb  = (n + 63) / 64;       // 1563
    int ab  = (n + 3) / 4;         // 25000

    convert_w<<<96, 256, 0, stream>>>(W1r, W1o, W2r, W2o, W3r, W3o, wt, bucketCnt);
    bucket_scatter<<<eb1, 1024, 0, stream>>>(src, dstl, bucketCnt, store, E);
    scan_buckets<<<1, 256, 0, stream>>>(bucketCnt, bucketBase, offs, nb, n, E);
    bucket_build<<<nb, 1024, 0, stream>>>(bucketCnt, bucketBase, store, offs, src_sorted, n);

    float* out = (float*)d_out;
    float* y1 = out;
    float* y2 = out + (size_t)n * D;
    float* y3 = out + 2 * (size_t)n * D;

    // layer 1 (ELU)
    gemm_ro<<<tb, 256, 0, stream>>>(graph, wtR1, wtO1, b1, hrel, hroot, n);
    agg_act<0><<<ab, 256, 0, stream>>>(hrel, hroot, offs, src_sorted, y1, n);
    // layer 2 (ELU)
    gemm_ro<<<tb, 256, 0, stream>>>(y1, wtR2, wtO2, b2, hrel, hroot, n);
    agg_act<0><<<ab, 256, 0, stream>>>(hrel, hroot, offs, src_sorted, y2, n);
    // layer 3 (sigmoid)
    gemm_ro<<<tb, 256, 0, stream>>>(y2, wtR3, wtO3, b3, hrel, hroot, n);
    agg_act<1><<<ab, 256, 0, stream>>>(hrel, hroot, offs, src_sorted, y3, n);
}